// Round 10
// baseline (37.238 us; speedup 1.0000x reference)
//
#include <hip/hip_runtime.h>
#include <math.h>

// MPDO chain via MFMA + PAIR-product table (L2-resident tier).
//   per b: edge = Pi_t M_t (64x64), M_t = sum_k A_k (x) B_k; out = log(tr(edge))
//
// Model (R3-R9): per-SIMD MFMA rate = one 32x32x16 per ~32 cyc => 16 MFMA/step
// = 512 cyc floor (MfmaUtil 32% at ~1600cyc steps matches). Residual is the
// within-wave serial path: 4x depth-4 MFMA chains -> full relayout -> repeat.
// R10 restructure: column-pipelined split-k schedule:
//   * Bf col ct depends only on acc col ct -> process col0 then col1; col1's
//     relayout VALU overlaps col0's MFMA pipe time.
//   * kt-sum split into 2 depth-2 chains/tile merged by f32 add -> 8
//     independent chains/step (was 4 depth-4) -> half dep critical path.
//   * 8 prefetch loads split between the two column phases.
// Unchanged (verified): prep2, ballot/SALU combo extraction, zc C-operand,
// depth-2 A0/A1/A2 rotation, trace, log. Scale 4^-64 -> log += 64*ln4.
// Fallback: ws < 4MB -> verified fp32 VALU kernel.

#define NSITES 64
#define NPAIRS 32

typedef short  s16x8  __attribute__((ext_vector_type(8)));
typedef float  f32x16 __attribute__((ext_vector_type(16)));

union Frag { unsigned int u[4]; s16x8 v; uint4 q; };

// ---------- prep2: (1/16)*P^T for all (pair, combo) — verified R5 ----------
__global__ __launch_bounds__(64)
void mpdo_prep2(const float* __restrict__ T, uint4* __restrict__ Mfp) {
    const int blk = blockIdx.x;              // 32 pairs * 16 combos
    const int pair = blk >> 4, combo = blk & 15;
    const int c0 = combo >> 2, c1 = combo & 3;
    const int ir0 = c0 >> 1, ic0 = c0 & 1, ir1 = c1 >> 1, ic1 = c1 & 1;
    const int lane = threadIdx.x;
    const int site0 = 2 * pair, site1 = 2 * pair + 1;

    __shared__ float sT0[256], sT1[256], sT2[256], sT3[256];
    __shared__ float sPA[16 * 64], sPB[16 * 64];

    *(float4*)&sT0[lane * 4] = *(const float4*)(T + ((size_t)(site0 * 2 + ir0)) * 256 + lane * 4);
    *(float4*)&sT1[lane * 4] = *(const float4*)(T + ((size_t)(site0 * 2 + ic0)) * 256 + lane * 4);
    *(float4*)&sT2[lane * 4] = *(const float4*)(T + ((size_t)(site1 * 2 + ir1)) * 256 + lane * 4);
    *(float4*)&sT3[lane * 4] = *(const float4*)(T + ((size_t)(site1 * 2 + ic1)) * 256 + lane * 4);
    __syncthreads();

    {
        const int i = lane >> 3, j = lane & 7;
        float pa[4][4], pb[4][4];
#pragma unroll
        for (int k = 0; k < 4; ++k)
#pragma unroll
            for (int jp = 0; jp < 4; ++jp) { pa[k][jp] = 0.0f; pb[k][jp] = 0.0f; }
#pragma unroll
        for (int a = 0; a < 8; ++a) {
            float4 x0 = *(const float4*)&sT0[(i * 8 + a) * 4];
            float4 y0 = *(const float4*)&sT2[(a * 8 + j) * 4];
            float4 x1 = *(const float4*)&sT1[(i * 8 + a) * 4];
            float4 y1 = *(const float4*)&sT3[(a * 8 + j) * 4];
            const float xk0[4] = {x0.x, x0.y, x0.z, x0.w};
            const float yj0[4] = {y0.x, y0.y, y0.z, y0.w};
            const float xk1[4] = {x1.x, x1.y, x1.z, x1.w};
            const float yj1[4] = {y1.x, y1.y, y1.z, y1.w};
#pragma unroll
            for (int k = 0; k < 4; ++k)
#pragma unroll
                for (int jp = 0; jp < 4; ++jp) {
                    pa[k][jp] = fmaf(xk0[k], yj0[jp], pa[k][jp]);
                    pb[k][jp] = fmaf(xk1[k], yj1[jp], pb[k][jp]);
                }
        }
#pragma unroll
        for (int k = 0; k < 4; ++k)
#pragma unroll
            for (int jp = 0; jp < 4; ++jp) {
                sPA[(k * 4 + jp) * 64 + lane] = pa[k][jp];
                sPB[(k * 4 + jp) * 64 + lane] = pb[k][jp];
            }
    }
    __syncthreads();

    const int h = lane >> 5, r = lane & 31, m = r & 7, j2 = r >> 3;
    float acc[8][8];
#pragma unroll
    for (int f = 0; f < 8; ++f)
#pragma unroll
        for (int e = 0; e < 8; ++e) acc[f][e] = 0.0f;

#pragma unroll 4
    for (int c = 0; c < 16; ++c) {
        float paf[8], pbe[8];
#pragma unroll
        for (int ti = 0; ti < 2; ++ti)
#pragma unroll
            for (int kt = 0; kt < 4; ++kt)
                paf[ti * 4 + kt] = sPA[c * 64 + (2 * kt + h) * 8 + (4 * ti + j2)];
#pragma unroll
        for (int e = 0; e < 8; ++e) pbe[e] = sPB[c * 64 + e * 8 + m];
#pragma unroll
        for (int f = 0; f < 8; ++f)
#pragma unroll
            for (int e = 0; e < 8; ++e)
                acc[f][e] = fmaf(paf[f], pbe[e], acc[f][e]);
    }

#pragma unroll
    for (int f = 0; f < 8; ++f) {
        unsigned int wds[4];
#pragma unroll
        for (int q = 0; q < 4; ++q) {
            float v0 = acc[f][2 * q]     * 0.0625f;
            float v1 = acc[f][2 * q + 1] * 0.0625f;
            asm("v_cvt_pk_bf16_f32 %0, %1, %2" : "=v"(wds[q]) : "v"(v0), "v"(v1));
        }
        Mfp[((size_t)(pair * 16 + combo) * 8 + f) * 64 + lane] =
            make_uint4(wds[0], wds[1], wds[2], wds[3]);
    }
}

// ---------- main: 1 wave/b, 32 steps, column-pipelined split-k ----------
__global__ __launch_bounds__(64, 1)
void mpdo_mfmaP3(const int* __restrict__ qn, const uint4* __restrict__ Mfp,
                 float* __restrict__ out) {
    const int b = blockIdx.x;
    const int lane = threadIdx.x;
    const int* qb = qn + (size_t)b * (2 * NSITES);
    const int pi = lane & 31;
    const int pc = (qb[2 * pi] << 3) | (qb[64 + 2 * pi] << 2) |
                   (qb[2 * pi + 1] << 1) | (qb[64 + 2 * pi + 1]);
    const unsigned long long m3 = __ballot(pc & 8);
    const unsigned long long m2 = __ballot(pc & 4);
    const unsigned long long m1 = __ballot(pc & 2);
    const unsigned long long m0 = __ballot(pc & 1);
    const int col = lane & 31, hh = lane >> 5;
    const int laneoff = lane * 16;

    f32x16 acc[2][2];   // X, C-layout
#pragma unroll
    for (int rt = 0; rt < 2; ++rt)
#pragma unroll
        for (int ct = 0; ct < 2; ++ct)
#pragma unroll
            for (int g = 0; g < 16; ++g) {
                int row = (g & 3) + 8 * (g >> 2) + 4 * hh;
                acc[rt][ct][g] = (rt == ct && row == col) ? 1.0f : 0.0f;
            }

    const f32x16 zc = {};   // persistent zero C-operand

    const char* Mbase = (const char*)Mfp;
    Frag A0[2][4], A1[2][4], A2[2][4];

#define COMBO(T_) ((int)(((((m3) >> (T_)) & 1ull) << 3) | ((((m2) >> (T_)) & 1ull) << 2) | \
                         ((((m1) >> (T_)) & 1ull) << 1) | (((m0) >> (T_)) & 1ull)))
#define LOAD_HALF(DST, PIDX, TI)                                               \
    {                                                                          \
        int c_ = COMBO(PIDX);                                                  \
        const char* nb_ = Mbase + (((size_t)(PIDX) * 16 + c_) << 13) + laneoff;\
        _Pragma("unroll")                                                      \
        for (int kt = 0; kt < 4; ++kt)                                         \
            DST[TI][kt].q = *(const uint4*)(nb_ + ((TI) * 4 + kt) * 1024);     \
    }
#define LOAD_FRAGS(DST, PIDX) { LOAD_HALF(DST, PIDX, 0) LOAD_HALF(DST, PIDX, 1) }

// build 4 B-frag slabs for one column ct from acc[0][ct], acc[1][ct]
#define MAKE_BF_COL(BF, CT)                                                   \
    {                                                                         \
        _Pragma("unroll")                                                     \
        for (int rt = 0; rt < 2; ++rt) {                                      \
            unsigned int w0[4], w1[4];                                        \
            _Pragma("unroll")                                                 \
            for (int q = 0; q < 4; ++q) {                                     \
                asm("v_cvt_pk_bf16_f32 %0, %1, %2"                            \
                    : "=v"(w0[q])                                             \
                    : "v"(acc[rt][CT][4 * q + 0]),                            \
                      "v"(acc[rt][CT][4 * q + 1]));                           \
                asm("v_cvt_pk_bf16_f32 %0, %1, %2"                            \
                    : "=v"(w1[q])                                             \
                    : "v"(acc[rt][CT][4 * q + 2]),                            \
                      "v"(acc[rt][CT][4 * q + 3]));                           \
            }                                                                 \
            _Pragma("unroll")                                                 \
            for (int kp = 0; kp < 2; ++kp) {                                  \
                unsigned int x0 = w0[2 * kp], y0 = w0[2 * kp + 1];            \
                asm("v_permlane32_swap_b32 %0, %1" : "+v"(x0), "+v"(y0));     \
                unsigned int x1 = w1[2 * kp], y1 = w1[2 * kp + 1];            \
                asm("v_permlane32_swap_b32 %0, %1" : "+v"(x1), "+v"(y1));     \
                BF[2 * rt + kp].u[0] = x0; BF[2 * rt + kp].u[1] = x1;         \
                BF[2 * rt + kp].u[2] = y0; BF[2 * rt + kp].u[3] = y1;         \
            }                                                                 \
        }                                                                     \
    }

// one output column: 4 independent depth-2 chains + packed adds
#define COL_MFMA(CUR, BF, CT)                                                 \
    {                                                                         \
        _Pragma("unroll")                                                     \
        for (int ti = 0; ti < 2; ++ti) {                                      \
            f32x16 p0 = __builtin_amdgcn_mfma_f32_32x32x16_bf16(              \
                CUR[ti][0].v, BF[0].v, zc, 0, 0, 0);                          \
            f32x16 p1 = __builtin_amdgcn_mfma_f32_32x32x16_bf16(              \
                CUR[ti][2].v, BF[2].v, zc, 0, 0, 0);                          \
            p0 = __builtin_amdgcn_mfma_f32_32x32x16_bf16(                     \
                CUR[ti][1].v, BF[1].v, p0, 0, 0, 0);                          \
            p1 = __builtin_amdgcn_mfma_f32_32x32x16_bf16(                     \
                CUR[ti][3].v, BF[3].v, p1, 0, 0, 0);                          \
            acc[ti][CT] = p0 + p1;                                            \
        }                                                                     \
    }

    LOAD_FRAGS(A0, 0)
    LOAD_FRAGS(A1, 1)

#define SITE_BODY(T_, CUR, NXT)                                               \
    {                                                                         \
        int tn = (T_) + 2; if (tn > 31) tn = 31;                              \
        Frag BfA[4];                                                          \
        MAKE_BF_COL(BfA, 0)                                                   \
        LOAD_HALF(NXT, tn, 0)                                                 \
        COL_MFMA(CUR, BfA, 0)                                                 \
        Frag BfB[4];                                                          \
        MAKE_BF_COL(BfB, 1)                                                   \
        LOAD_HALF(NXT, tn, 1)                                                 \
        COL_MFMA(CUR, BfB, 1)                                                 \
    }

#pragma unroll 1
    for (int t = 0; t < 30; t += 3) {
        SITE_BODY(t,     A0, A2)
        SITE_BODY(t + 1, A1, A0)
        SITE_BODY(t + 2, A2, A1)
    }
    SITE_BODY(30, A0, A2)   // tail prefetches clamp to pair 31 (discarded)
    SITE_BODY(31, A1, A0)
#undef SITE_BODY
#undef COL_MFMA
#undef MAKE_BF_COL
#undef LOAD_FRAGS
#undef LOAD_HALF
#undef COMBO

    // trace (X = full product transposed; trace invariant)
    float diag = 0.0f;
#pragma unroll
    for (int tt = 0; tt < 2; ++tt)
#pragma unroll
        for (int g = 0; g < 16; ++g) {
            int row = (g & 3) + 8 * (g >> 2) + 4 * hh;
            if (row == col) diag += acc[tt][tt][g];
        }
#pragma unroll
    for (int off = 32; off >= 1; off >>= 1)
        diag += __shfl_xor(diag, off, 64);

    if (lane == 0) {
        float tr = diag;
        float re = logf(fabsf(tr)) + 64.0f * 1.3862943611198906f;  // undo 4^-64
        float im = (tr < 0.0f) ? 3.14159265358979323846f : 0.0f;
        out[2 * b]     = re;
        out[2 * b + 1] = im;
    }
}

// ---------- fallback fp32 VALU kernel (verified R2) ----------
#define DD 8
#define KCHI 4
__global__ __launch_bounds__(64, 1)
void mpdo_chain(const int* __restrict__ qn, const float* __restrict__ T,
                float* __restrict__ out) {
    const int b = blockIdx.x;
    const int lane = threadIdx.x;
    __shared__ float sA[KCHI][DD][DD];
    __shared__ float sB[KCHI][DD][DD];
    float E[DD][DD];
#pragma unroll
    for (int i = 0; i < DD; ++i)
#pragma unroll
        for (int l = 0; l < DD; ++l) E[i][l] = (i * DD + l == lane) ? 1.0f : 0.0f;
    const int* qb = qn + (size_t)b * (2 * NSITES);
    int ir0 = qb[0], ic0 = qb[NSITES];
    float4 aP = *reinterpret_cast<const float4*>(T + (size_t)ir0 * 256 + lane * 4);
    float4 bP = *reinterpret_cast<const float4*>(T + (size_t)ic0 * 256 + lane * 4);
    const int li = lane >> 3, lj = lane & 7;
#pragma unroll 1
    for (int site = 0; site < NSITES; ++site) {
        __syncthreads();
        sA[0][li][lj] = 0.5f * aP.x; sA[1][li][lj] = 0.5f * aP.y;
        sA[2][li][lj] = 0.5f * aP.z; sA[3][li][lj] = 0.5f * aP.w;
        sB[0][li][lj] = 0.5f * bP.x; sB[1][li][lj] = 0.5f * bP.y;
        sB[2][li][lj] = 0.5f * bP.z; sB[3][li][lj] = 0.5f * bP.w;
        __syncthreads();
        if (site + 1 < NSITES) {
            int irn = qb[site + 1], icn = qb[NSITES + site + 1];
            aP = *reinterpret_cast<const float4*>(T + ((size_t)(site + 1) * 2 + irn) * 256 + lane * 4);
            bP = *reinterpret_cast<const float4*>(T + ((size_t)(site + 1) * 2 + icn) * 256 + lane * 4);
        }
        float Ep[DD][DD];
#pragma unroll
        for (int j = 0; j < DD; ++j)
#pragma unroll
            for (int m = 0; m < DD; ++m) Ep[j][m] = 0.0f;
#pragma unroll 1
        for (int k = 0; k < KCHI; ++k) {
            float tmp[DD][DD];
#pragma unroll
            for (int l = 0; l < DD; ++l) {
                const float4* bp = reinterpret_cast<const float4*>(&sB[k][l][0]);
                float4 b0 = bp[0], b1 = bp[1];
                float brow[DD] = {b0.x, b0.y, b0.z, b0.w, b1.x, b1.y, b1.z, b1.w};
                if (l == 0) {
#pragma unroll
                    for (int i = 0; i < DD; ++i)
#pragma unroll
                        for (int m = 0; m < DD; ++m) tmp[i][m] = E[i][0] * brow[m];
                } else {
#pragma unroll
                    for (int i = 0; i < DD; ++i)
#pragma unroll
                        for (int m = 0; m < DD; ++m)
                            tmp[i][m] = fmaf(E[i][l], brow[m], tmp[i][m]);
                }
            }
#pragma unroll
            for (int i = 0; i < DD; ++i) {
                const float4* ap = reinterpret_cast<const float4*>(&sA[k][i][0]);
                float4 a0 = ap[0], a1 = ap[1];
                float arow[DD] = {a0.x, a0.y, a0.z, a0.w, a1.x, a1.y, a1.z, a1.w};
#pragma unroll
                for (int j = 0; j < DD; ++j)
#pragma unroll
                    for (int m = 0; m < DD; ++m)
                        Ep[j][m] = fmaf(arow[j], tmp[i][m], Ep[j][m]);
            }
        }
#pragma unroll
        for (int i = 0; i < DD; ++i)
#pragma unroll
            for (int l = 0; l < DD; ++l) E[i][l] = Ep[i][l];
    }
    float diag = 0.0f;
#pragma unroll
    for (int i = 0; i < DD; ++i)
#pragma unroll
        for (int l = 0; l < DD; ++l) diag += (i * DD + l == lane) ? E[i][l] : 0.0f;
#pragma unroll
    for (int off = 32; off >= 1; off >>= 1) diag += __shfl_xor(diag, off, 64);
    if (lane == 0) {
        float tr = diag;
        out[2 * b]     = logf(fabsf(tr)) + 64.0f * 1.3862943611198906f;
        out[2 * b + 1] = (tr < 0.0f) ? 3.14159265358979323846f : 0.0f;
    }
}

extern "C" void kernel_launch(void* const* d_in, const int* in_sizes, int n_in,
                              void* d_out, int out_size, void* d_ws, size_t ws_size,
                              hipStream_t stream) {
    const int*   qn  = (const int*)d_in[0];
    const float* T   = (const float*)d_in[1];
    float*       out = (float*)d_out;
    const int B = in_sizes[0] / (2 * NSITES);
    const size_t WS_PAIR = (size_t)NPAIRS * 16 * 8 * 64 * 16;  // 4 MB
    if (ws_size >= WS_PAIR) {
        uint4* Mfp = (uint4*)d_ws;
        mpdo_prep2<<<dim3(NPAIRS * 16), dim3(64), 0, stream>>>(T, Mfp);
        mpdo_mfmaP3<<<dim3(B), dim3(64), 0, stream>>>(qn, Mfp, out);
    } else {
        mpdo_chain<<<dim3(B), dim3(64), 0, stream>>>(qn, T, out);
    }
}

// Round 11
// 29.903 us; speedup vs baseline: 1.2453x; 1.2453x over previous
//
#include <hip/hip_runtime.h>
#include <math.h>

// MPDO chain via MFMA + fp8 DELTA pair table.
//   per b: edge = Pi_t M_t (64x64), M_t = sum_k A_k (x) B_k; out = log(tr(edge))
//
// Ledger: issue-work cuts null (R8/R9), wave-ILP null (R4), chain-ILP neg
// (R10), >L2 table neg (R7). Invariant: ~8KB table flow per step pins step
// cost (~20 B/cyc/CU). R11 halves bytes without fp8-level error:
//   P/16 = I + D (tensors ~ I + 0.01 noise => |D| ~ 0.05-0.2).
//   Table stores D^T in fp8 e4m3 (4 KB/entry, 2 MB total, L2-resident).
//   Step: acc <- mfma-chain(D^T_frags, fp8(acc), C-in = acc)  == (I+D)X with
//   the identity term carried EXACTLY in f32 (C operand) - fp8 error only on
//   the O(0.1) update -> ~0.05 log error (~ bf16 quality).
//   4x dwordx4 loads/step (was 8), 16 MFMA (fp8 rate = bf16 rate), relayout
//   32 cvt_pk_fp8 + 8 permlane32_swap (hh-crossing re-derived for byte-K).
// Unchanged (verified): prep2 Kron algebra, ballot/SALU combos, depth-2
// rotation, trace, log += 64*ln4.
// Fallback: ws < 2MB -> verified fp32 VALU kernel.

#define NSITES 64
#define NPAIRS 32

typedef float f32x16 __attribute__((ext_vector_type(16)));

// pack 4 f32 -> 1 dword of 4 fp8 e4m3 (bytes 0..3)
#define PACK4(P, A0, A1, A2, A3)                                               \
    asm("v_cvt_pk_fp8_f32 %0, %1, %2" : "=v"(P) : "v"(A0), "v"(A1));           \
    asm("v_cvt_pk_fp8_f32 %0, %1, %2 op_sel:[0,0,1]" : "+v"(P) : "v"(A2), "v"(A3));

// ---------- prep2f8: D^T = (1/16)P^T - I in fp8 for all (pair,combo) ----------
__global__ __launch_bounds__(64)
void mpdo_prep2f8(const float* __restrict__ T, uint4* __restrict__ Mf8) {
    const int blk = blockIdx.x;              // 32 pairs * 16 combos
    const int pair = blk >> 4, combo = blk & 15;
    const int c0 = combo >> 2, c1 = combo & 3;
    const int ir0 = c0 >> 1, ic0 = c0 & 1, ir1 = c1 >> 1, ic1 = c1 & 1;
    const int lane = threadIdx.x;
    const int site0 = 2 * pair, site1 = 2 * pair + 1;

    __shared__ float sT0[256], sT1[256], sT2[256], sT3[256];
    __shared__ float sPA[16 * 64], sPB[16 * 64];

    *(float4*)&sT0[lane * 4] = *(const float4*)(T + ((size_t)(site0 * 2 + ir0)) * 256 + lane * 4);
    *(float4*)&sT1[lane * 4] = *(const float4*)(T + ((size_t)(site0 * 2 + ic0)) * 256 + lane * 4);
    *(float4*)&sT2[lane * 4] = *(const float4*)(T + ((size_t)(site1 * 2 + ir1)) * 256 + lane * 4);
    *(float4*)&sT3[lane * 4] = *(const float4*)(T + ((size_t)(site1 * 2 + ic1)) * 256 + lane * 4);
    __syncthreads();

    {   // PA_c[i][j] = sum_a Tr0[i][a][k]*Tr1[a][j][jp]; PB analogous
        const int i = lane >> 3, j = lane & 7;
        float pa[4][4], pb[4][4];
#pragma unroll
        for (int k = 0; k < 4; ++k)
#pragma unroll
            for (int jp = 0; jp < 4; ++jp) { pa[k][jp] = 0.0f; pb[k][jp] = 0.0f; }
#pragma unroll
        for (int a = 0; a < 8; ++a) {
            float4 x0 = *(const float4*)&sT0[(i * 8 + a) * 4];
            float4 y0 = *(const float4*)&sT2[(a * 8 + j) * 4];
            float4 x1 = *(const float4*)&sT1[(i * 8 + a) * 4];
            float4 y1 = *(const float4*)&sT3[(a * 8 + j) * 4];
            const float xk0[4] = {x0.x, x0.y, x0.z, x0.w};
            const float yj0[4] = {y0.x, y0.y, y0.z, y0.w};
            const float xk1[4] = {x1.x, x1.y, x1.z, x1.w};
            const float yj1[4] = {y1.x, y1.y, y1.z, y1.w};
#pragma unroll
            for (int k = 0; k < 4; ++k)
#pragma unroll
                for (int jp = 0; jp < 4; ++jp) {
                    pa[k][jp] = fmaf(xk0[k], yj0[jp], pa[k][jp]);
                    pb[k][jp] = fmaf(xk1[k], yj1[jp], pb[k][jp]);
                }
        }
#pragma unroll
        for (int k = 0; k < 4; ++k)
#pragma unroll
            for (int jp = 0; jp < 4; ++jp) {
                sPA[(k * 4 + jp) * 64 + lane] = pa[k][jp];
                sPB[(k * 4 + jp) * 64 + lane] = pb[k][jp];
            }
    }
    __syncthreads();

    const int h = lane >> 5, r = lane & 31, m = r & 7, j2 = r >> 3;
    float acc[8][8];
#pragma unroll
    for (int f = 0; f < 8; ++f)
#pragma unroll
        for (int e = 0; e < 8; ++e) acc[f][e] = 0.0f;

#pragma unroll 4
    for (int c = 0; c < 16; ++c) {
        float paf[8], pbe[8];
#pragma unroll
        for (int ti = 0; ti < 2; ++ti)
#pragma unroll
            for (int kt = 0; kt < 4; ++kt)
                paf[ti * 4 + kt] = sPA[c * 64 + (2 * kt + h) * 8 + (4 * ti + j2)];
#pragma unroll
        for (int e = 0; e < 8; ++e) pbe[e] = sPB[c * 64 + e * 8 + m];
#pragma unroll
        for (int f = 0; f < 8; ++f)
#pragma unroll
            for (int e = 0; e < 8; ++e)
                acc[f][e] = fmaf(paf[f], pbe[e], acc[f][e]);
    }

    // store D^T = (1/16)P^T - I as fp8, two frags per uint4
#pragma unroll
    for (int fp = 0; fp < 4; ++fp) {
        unsigned d[4];
#pragma unroll
        for (int s = 0; s < 2; ++s) {
            const int f = 2 * fp + s;
            const int ti = f >> 2, kt = f & 3;
            float Fv[8];
#pragma unroll
            for (int e = 0; e < 8; ++e) {
                float w = acc[f][e] * 0.0625f;
                if (32 * ti + r == 16 * kt + 8 * h + e) w -= 1.0f;
                Fv[e] = w;
            }
            PACK4(d[2 * s],     Fv[0], Fv[1], Fv[2], Fv[3])
            PACK4(d[2 * s + 1], Fv[4], Fv[5], Fv[6], Fv[7])
        }
        Mf8[((size_t)(pair * 16 + combo) * 4 + fp) * 64 + lane] =
            make_uint4(d[0], d[1], d[2], d[3]);
    }
}

// ---------- main: 1 wave/b, 32 steps, fp8-delta updates ----------
__global__ __launch_bounds__(64, 1)
void mpdo_mfmaF8(const int* __restrict__ qn, const uint4* __restrict__ Mf8,
                 float* __restrict__ out) {
    const int b = blockIdx.x;
    const int lane = threadIdx.x;
    const int* qb = qn + (size_t)b * (2 * NSITES);
    const int pi = lane & 31;
    const int pc = (qb[2 * pi] << 3) | (qb[64 + 2 * pi] << 2) |
                   (qb[2 * pi + 1] << 1) | (qb[64 + 2 * pi + 1]);
    const unsigned long long m3 = __ballot(pc & 8);
    const unsigned long long m2 = __ballot(pc & 4);
    const unsigned long long m1 = __ballot(pc & 2);
    const unsigned long long m0 = __ballot(pc & 1);
    const int col = lane & 31, hh = lane >> 5;
    const int laneoff = lane * 16;

    f32x16 acc[2][2];   // X, C-layout: row=32*rt+(g&3)+8*(g>>2)+4*hh, col=32*ct+col
#pragma unroll
    for (int rt = 0; rt < 2; ++rt)
#pragma unroll
        for (int ct = 0; ct < 2; ++ct)
#pragma unroll
            for (int g = 0; g < 16; ++g) {
                int row = (g & 3) + 8 * (g >> 2) + 4 * hh;
                acc[rt][ct][g] = (rt == ct && row == col) ? 1.0f : 0.0f;
            }

    const char* Mbase = (const char*)Mf8;
    uint4 A0[4], A1[4], A2[4];   // frag-pairs: A[fp] = frags 2fp,2fp+1

#define COMBO(T_) ((int)(((((m3) >> (T_)) & 1ull) << 3) | ((((m2) >> (T_)) & 1ull) << 2) | \
                         ((((m1) >> (T_)) & 1ull) << 1) | (((m0) >> (T_)) & 1ull)))
#define LOAD_FRAGS(DST, PIDX)                                                  \
    {                                                                          \
        int c_ = COMBO(PIDX);                                                  \
        const char* nb_ = Mbase + (((size_t)(PIDX) * 16 + c_) << 12) + laneoff;\
        _Pragma("unroll")                                                      \
        for (int fp = 0; fp < 4; ++fp)                                         \
            DST[fp] = *(const uint4*)(nb_ + fp * 1024);                        \
    }
// i64 A-operand for frag f from frag-pair array
#define A64(CUR, F)                                                            \
    (((F) & 1) ? (((unsigned long long)CUR[(F) >> 1].w << 32) | CUR[(F) >> 1].z) \
               : (((unsigned long long)CUR[(F) >> 1].y << 32) | CUR[(F) >> 1].x))

    LOAD_FRAGS(A0, 0)
    LOAD_FRAGS(A1, 1)

#define SITE_BODY(T_, CUR, NXT)                                               \
    {                                                                         \
        int tn = (T_) + 2; if (tn > 31) tn = 31;                              \
        LOAD_FRAGS(NXT, tn)                                                   \
        /* B-frags: fp8(acc). kt=2rt: g0..7; kt=2rt+1: g8..15.            */  \
        /* dword0 = e0..3, dword1 = e4..7 after permlane32_swap(u,v).     */  \
        unsigned bf[4][2][2]; /* [kt][ct][dword] */                           \
        _Pragma("unroll")                                                     \
        for (int rt = 0; rt < 2; ++rt)                                        \
            _Pragma("unroll")                                                 \
            for (int ct = 0; ct < 2; ++ct) {                                  \
                unsigned u, v, u2, v2;                                        \
                PACK4(u,  acc[rt][ct][0],  acc[rt][ct][1],                    \
                          acc[rt][ct][2],  acc[rt][ct][3])                    \
                PACK4(v,  acc[rt][ct][4],  acc[rt][ct][5],                    \
                          acc[rt][ct][6],  acc[rt][ct][7])                    \
                asm("v_permlane32_swap_b32 %0, %1" : "+v"(u), "+v"(v));       \
                bf[2 * rt][ct][0] = u; bf[2 * rt][ct][1] = v;                 \
                PACK4(u2, acc[rt][ct][8],  acc[rt][ct][9],                    \
                          acc[rt][ct][10], acc[rt][ct][11])                   \
                PACK4(v2, acc[rt][ct][12], acc[rt][ct][13],                   \
                          acc[rt][ct][14], acc[rt][ct][15])                   \
                asm("v_permlane32_swap_b32 %0, %1" : "+v"(u2), "+v"(v2));     \
                bf[2 * rt + 1][ct][0] = u2; bf[2 * rt + 1][ct][1] = v2;       \
            }                                                                 \
        /* X <- X + D^T X : C-in = old acc carries the identity exactly */    \
        _Pragma("unroll")                                                     \
        for (int ti = 0; ti < 2; ++ti)                                        \
            _Pragma("unroll")                                                 \
            for (int tj = 0; tj < 2; ++tj) {                                  \
                f32x16 d = acc[ti][tj];                                       \
                _Pragma("unroll")                                             \
                for (int kt = 0; kt < 4; ++kt) {                              \
                    unsigned long long av = A64(CUR, ti * 4 + kt);            \
                    unsigned long long bv =                                   \
                        ((unsigned long long)bf[kt][tj][1] << 32) |           \
                        bf[kt][tj][0];                                        \
                    d = __builtin_amdgcn_mfma_f32_32x32x16_fp8_fp8(           \
                        (long)av, (long)bv, d, 0, 0, 0);                      \
                }                                                             \
                acc[ti][tj] = d;                                              \
            }                                                                 \
    }

#pragma unroll 1
    for (int t = 0; t < 30; t += 3) {
        SITE_BODY(t,     A0, A2)
        SITE_BODY(t + 1, A1, A0)
        SITE_BODY(t + 2, A2, A1)
    }
    SITE_BODY(30, A0, A2)   // tail prefetches clamp to pair 31 (discarded)
    SITE_BODY(31, A1, A0)
#undef SITE_BODY
#undef LOAD_FRAGS
#undef A64
#undef COMBO

    // trace (X = full product transposed; trace invariant)
    float diag = 0.0f;
#pragma unroll
    for (int tt = 0; tt < 2; ++tt)
#pragma unroll
        for (int g = 0; g < 16; ++g) {
            int row = (g & 3) + 8 * (g >> 2) + 4 * hh;
            if (row == col) diag += acc[tt][tt][g];
        }
#pragma unroll
    for (int off = 32; off >= 1; off >>= 1)
        diag += __shfl_xor(diag, off, 64);

    if (lane == 0) {
        float tr = diag;
        float re = logf(fabsf(tr)) + 64.0f * 1.3862943611198906f;  // undo 4^-64
        float im = (tr < 0.0f) ? 3.14159265358979323846f : 0.0f;
        out[2 * b]     = re;
        out[2 * b + 1] = im;
    }
}

// ---------- fallback fp32 VALU kernel (verified R2) ----------
#define DD 8
#define KCHI 4
__global__ __launch_bounds__(64, 1)
void mpdo_chain(const int* __restrict__ qn, const float* __restrict__ T,
                float* __restrict__ out) {
    const int b = blockIdx.x;
    const int lane = threadIdx.x;
    __shared__ float sA[KCHI][DD][DD];
    __shared__ float sB[KCHI][DD][DD];
    float E[DD][DD];
#pragma unroll
    for (int i = 0; i < DD; ++i)
#pragma unroll
        for (int l = 0; l < DD; ++l) E[i][l] = (i * DD + l == lane) ? 1.0f : 0.0f;
    const int* qb = qn + (size_t)b * (2 * NSITES);
    int ir0 = qb[0], ic0 = qb[NSITES];
    float4 aP = *reinterpret_cast<const float4*>(T + (size_t)ir0 * 256 + lane * 4);
    float4 bP = *reinterpret_cast<const float4*>(T + (size_t)ic0 * 256 + lane * 4);
    const int li = lane >> 3, lj = lane & 7;
#pragma unroll 1
    for (int site = 0; site < NSITES; ++site) {
        __syncthreads();
        sA[0][li][lj] = 0.5f * aP.x; sA[1][li][lj] = 0.5f * aP.y;
        sA[2][li][lj] = 0.5f * aP.z; sA[3][li][lj] = 0.5f * aP.w;
        sB[0][li][lj] = 0.5f * bP.x; sB[1][li][lj] = 0.5f * bP.y;
        sB[2][li][lj] = 0.5f * bP.z; sB[3][li][lj] = 0.5f * bP.w;
        __syncthreads();
        if (site + 1 < NSITES) {
            int irn = qb[site + 1], icn = qb[NSITES + site + 1];
            aP = *reinterpret_cast<const float4*>(T + ((size_t)(site + 1) * 2 + irn) * 256 + lane * 4);
            bP = *reinterpret_cast<const float4*>(T + ((size_t)(site + 1) * 2 + icn) * 256 + lane * 4);
        }
        float Ep[DD][DD];
#pragma unroll
        for (int j = 0; j < DD; ++j)
#pragma unroll
            for (int m = 0; m < DD; ++m) Ep[j][m] = 0.0f;
#pragma unroll 1
        for (int k = 0; k < KCHI; ++k) {
            float tmp[DD][DD];
#pragma unroll
            for (int l = 0; l < DD; ++l) {
                const float4* bp = reinterpret_cast<const float4*>(&sB[k][l][0]);
                float4 b0 = bp[0], b1 = bp[1];
                float brow[DD] = {b0.x, b0.y, b0.z, b0.w, b1.x, b1.y, b1.z, b1.w};
                if (l == 0) {
#pragma unroll
                    for (int i = 0; i < DD; ++i)
#pragma unroll
                        for (int m = 0; m < DD; ++m) tmp[i][m] = E[i][0] * brow[m];
                } else {
#pragma unroll
                    for (int i = 0; i < DD; ++i)
#pragma unroll
                        for (int m = 0; m < DD; ++m)
                            tmp[i][m] = fmaf(E[i][l], brow[m], tmp[i][m]);
                }
            }
#pragma unroll
            for (int i = 0; i < DD; ++i) {
                const float4* ap = reinterpret_cast<const float4*>(&sA[k][i][0]);
                float4 a0 = ap[0], a1 = ap[1];
                float arow[DD] = {a0.x, a0.y, a0.z, a0.w, a1.x, a1.y, a1.z, a1.w};
#pragma unroll
                for (int j = 0; j < DD; ++j)
#pragma unroll
                    for (int m = 0; m < DD; ++m)
                        Ep[j][m] = fmaf(arow[j], tmp[i][m], Ep[j][m]);
            }
        }
#pragma unroll
        for (int i = 0; i < DD; ++i)
#pragma unroll
            for (int l = 0; l < DD; ++l) E[i][l] = Ep[i][l];
    }
    float diag = 0.0f;
#pragma unroll
    for (int i = 0; i < DD; ++i)
#pragma unroll
        for (int l = 0; l < DD; ++l) diag += (i * DD + l == lane) ? E[i][l] : 0.0f;
#pragma unroll
    for (int off = 32; off >= 1; off >>= 1) diag += __shfl_xor(diag, off, 64);
    if (lane == 0) {
        float tr = diag;
        out[2 * b]     = logf(fabsf(tr)) + 64.0f * 1.3862943611198906f;
        out[2 * b + 1] = (tr < 0.0f) ? 3.14159265358979323846f : 0.0f;
    }
}

extern "C" void kernel_launch(void* const* d_in, const int* in_sizes, int n_in,
                              void* d_out, int out_size, void* d_ws, size_t ws_size,
                              hipStream_t stream) {
    const int*   qn  = (const int*)d_in[0];
    const float* T   = (const float*)d_in[1];
    float*       out = (float*)d_out;
    const int B = in_sizes[0] / (2 * NSITES);
    const size_t WS_F8 = (size_t)NPAIRS * 16 * 4 * 64 * 16;  // 2 MB
    if (ws_size >= WS_F8) {
        uint4* Mf8 = (uint4*)d_ws;
        mpdo_prep2f8<<<dim3(NPAIRS * 16), dim3(64), 0, stream>>>(T, Mf8);
        mpdo_mfmaF8<<<dim3(B), dim3(64), 0, stream>>>(qn, Mf8, out);
    } else {
        mpdo_chain<<<dim3(B), dim3(64), 0, stream>>>(qn, T, out);
    }
}